// Round 6
// baseline (128.251 us; speedup 1.0000x reference)
//
#include <hip/hip_runtime.h>
#include <math.h>

#define Bb 2
#define Ss 128
#define Hh 768
#define Cc 5
#define Mm 256       // Bb*Ss
#define NEGV -1024.0f
#define SCALE 2.8853900817779268f   // 2/ln(2): Ep*Ea = e^{2x}

// haTb: bf16 [b][c][h8][a][h&7], h8=h>>3 in [0,96)   -- stores Ea = exp2(scaled ha)
#define PT 2
#define NBLK (Mm / PT * Cc)   // 640

typedef __attribute__((ext_vector_type(8))) short bf16x8;
typedef __attribute__((ext_vector_type(4))) float f32x4;
typedef unsigned short ushort;

__device__ __forceinline__ unsigned pack_hi16(float hi, float lo) {
    return (__float_as_uint(hi) & 0xFFFF0000u) | (__float_as_uint(lo) >> 16);
}
__device__ __forceinline__ bf16x8 pack_bf16x8(float4 lo, float4 hi) {
    union { bf16x8 v; unsigned u[4]; } r;
    r.u[0] = pack_hi16(lo.y, lo.x);
    r.u[1] = pack_hi16(lo.w, lo.z);
    r.u[2] = pack_hi16(hi.y, hi.x);
    r.u[3] = pack_hi16(hi.w, hi.z);
    return r.v;
}
// round-to-nearest-even bf16 of f32
__device__ __forceinline__ ushort bf16_rne(float f) {
    unsigned b = __float_as_uint(f);
    return (ushort)((b + 0x7FFFu + ((b >> 16) & 1u)) >> 16);
}

#define SB __builtin_amdgcn_sched_barrier(0);

// ---------------- Kernel 1: LDS-staged bf16 MFMA GEMM ----------------
// K=64 LDS tiles (one barrier pair per 64-K instead of per 32-K: 48 -> 24
// barriers/block). 2-stage register prefetch. MFMA accumulation order is
// unchanged (k, then k+32) -> bit-identical to the previous version.

__global__ __launch_bounds__(256)
void gemm_mfma(const float* __restrict__ X,
               const float* __restrict__ Wprd,
               const float* __restrict__ Warg,
               const float* __restrict__ bprd,
               const float* __restrict__ barg,
               float* __restrict__ EpG,
               ushort* __restrict__ haTb,
               float* __restrict__ accum)
{
    __shared__ __align__(16) ushort Asb[64][72];   // 64 rows x 64 k (stride 72: 2-way-free)
    __shared__ __align__(16) ushort Bsb[32][72];

    if (blockIdx.x == 0 && blockIdx.y == 0 && threadIdx.x == 0) {
        accum[0] = 0.f; accum[1] = 0.f;
        ((unsigned*)accum)[2] = 0u;      // completion counter
    }
    const int bm   = blockIdx.x;          // 0..3   (64 rows)
    const int bn   = blockIdx.y;          // 0..143 (32 cols)
    const int tid  = threadIdx.x;
    const int wave = tid >> 6;
    const int lane = tid & 63;
    const int l16  = lane & 15;
    const int quad = lane >> 4;

    const float* Wsrc; const float* bsrc;
    const int nb = bn * 32;
    if (nb < Hh) { Wsrc = Wprd + (size_t)nb * Hh;        bsrc = bprd + nb; }
    else         { Wsrc = Warg + (size_t)(nb - Hh) * Hh; bsrc = barg + (nb - Hh); }

    const int srow = tid >> 2;
    const int sko  = (tid & 3) * 8;
    const float* gA = X + (size_t)(bm * 64 + srow) * Hh + sko;
    const float* gB = Wsrc + (size_t)(tid >> 2) * Hh + sko;   // valid for tid<128

    // stage regs: k and k+32
    float4 a00 = *(const float4*)(gA);
    float4 a01 = *(const float4*)(gA + 4);
    float4 a10 = *(const float4*)(gA + 32);
    float4 a11 = *(const float4*)(gA + 36);
    float4 b00, b01, b10, b11;
    if (tid < 128) {
        b00 = *(const float4*)(gB);      b01 = *(const float4*)(gB + 4);
        b10 = *(const float4*)(gB + 32); b11 = *(const float4*)(gB + 36);
    }

    f32x4 acc0 = {0.f,0.f,0.f,0.f}, acc1 = {0.f,0.f,0.f,0.f};

    for (int k0 = 0; k0 < Hh; k0 += 64) {
        *(bf16x8*)&Asb[srow][sko]      = pack_bf16x8(a00, a01);
        *(bf16x8*)&Asb[srow][sko + 32] = pack_bf16x8(a10, a11);
        if (tid < 128) {
            *(bf16x8*)&Bsb[tid >> 2][sko]      = pack_bf16x8(b00, b01);
            *(bf16x8*)&Bsb[tid >> 2][sko + 32] = pack_bf16x8(b10, b11);
        }
        __syncthreads();
        if (k0 + 64 < Hh) {
            a00 = *(const float4*)(gA + k0 + 64);
            a01 = *(const float4*)(gA + k0 + 68);
            a10 = *(const float4*)(gA + k0 + 96);
            a11 = *(const float4*)(gA + k0 + 100);
            if (tid < 128) {
                b00 = *(const float4*)(gB + k0 + 64);
                b01 = *(const float4*)(gB + k0 + 68);
                b10 = *(const float4*)(gB + k0 + 96);
                b11 = *(const float4*)(gB + k0 + 100);
            }
        }
        {
            bf16x8 af0 = *(const bf16x8*)&Asb[wave * 16 + l16][quad * 8];
            bf16x8 c00 = *(const bf16x8*)&Bsb[l16][quad * 8];
            bf16x8 c10 = *(const bf16x8*)&Bsb[16 + l16][quad * 8];
            acc0 = __builtin_amdgcn_mfma_f32_16x16x32_bf16(af0, c00, acc0, 0, 0, 0);
            acc1 = __builtin_amdgcn_mfma_f32_16x16x32_bf16(af0, c10, acc1, 0, 0, 0);
            bf16x8 af1 = *(const bf16x8*)&Asb[wave * 16 + l16][quad * 8 + 32];
            bf16x8 c01 = *(const bf16x8*)&Bsb[l16][quad * 8 + 32];
            bf16x8 c11 = *(const bf16x8*)&Bsb[16 + l16][quad * 8 + 32];
            acc0 = __builtin_amdgcn_mfma_f32_16x16x32_bf16(af1, c01, acc0, 0, 0, 0);
            acc1 = __builtin_amdgcn_mfma_f32_16x16x32_bf16(af1, c11, acc1, 0, 0, 0);
        }
        __syncthreads();
    }

    const float sb0 = SCALE * bsrc[l16];
    const float sb1 = SCALE * bsrc[16 + l16];
    const int row = bm * 64 + wave * 16 + quad * 4;

    if (nb < Hh) {   // Ep: row-major fp32 [m][h] = exp2(hp')
        #pragma unroll
        for (int r = 0; r < 4; ++r) {
            const int mm = row + r;
            EpG[(size_t)mm * Hh + nb + l16]      = __builtin_amdgcn_exp2f(SCALE * acc0[r] + sb0);
            EpG[(size_t)mm * Hh + nb + 16 + l16] = __builtin_amdgcn_exp2f(SCALE * acc1[r] + sb1);
        }
    } else {         // Ea = exp2(ha') -> haTb bf16 [b][c][h>>3][a][h&7]
        const int q  = nb - Hh;
        const int cU = q / Hh;
        const int h0 = q % Hh;
        const int hA = h0 + l16;
        const int hB = h0 + 16 + l16;
        const size_t offA = (size_t)(hA >> 3) * 1024 + (hA & 7);
        const size_t offB = (size_t)(hB >> 3) * 1024 + (hB & 7);
        #pragma unroll
        for (int r = 0; r < 4; ++r) {
            const int mm = row + r;
            const int bI = mm >> 7, aI = mm & 127;
            const size_t base = ((size_t)(bI * Cc + cU) * 96) * 1024 + (size_t)aI * 8;
            const float e0 = __builtin_amdgcn_exp2f(SCALE * acc0[r] + sb0);
            const float e1 = __builtin_amdgcn_exp2f(SCALE * acc1[r] + sb1);
            haTb[base + offA] = bf16_rne(e0);
            haTb[base + offB] = bf16_rne(e1);
        }
    }
}

// ---------------- Kernel 2: biaffine ----------------
// Grid 640 = (p-tile, c), 512 thr: tid = hq*128 + a. term = w * rcp(Ep*Ea + 1).
// w/ep staged in LDS (broadcast ds_read). Round-6 change: relax the schedule
// pins -- one sched_barrier per segment (after the segment's loads) instead of
// two. Lets the compiler pipeline next-C1 ds_reads and next-group global loads
// under the current rcp/fma chain (intra-wave ILP is the only latency-hiding
// resource at ~2.3 waves/SIMD).
#define LOADG4(R, g) \
    R##0 = hap4[((g)*4+0)*128]; R##1 = hap4[((g)*4+1)*128]; \
    R##2 = hap4[((g)*4+2)*128]; R##3 = hap4[((g)*4+3)*128];

// one h-term for both p rows; z parity picks the accumulator pair (same
// per-accumulator add order as before -> bit-identical results)
#define PAIR(z, ee) { \
    const float ww = wS[hx + (z)]; \
    const float r0 = __builtin_amdgcn_rcpf(fmaf(e0S[hx + (z)], (ee), 1.0f)); \
    const float r1 = __builtin_amdgcn_rcpf(fmaf(e1S[hx + (z)], (ee), 1.0f)); \
    if ((z) & 1) { ac01 = fmaf(ww, r0, ac01); ac11 = fmaf(ww, r1, ac11); } \
    else         { ac00 = fmaf(ww, r0, ac00); ac10 = fmaf(ww, r1, ac10); } \
}

#define C1(u, hx_) { \
    const int hx = (hx_); \
    PAIR(0, __uint_as_float((u).x << 16)) \
    PAIR(1, __uint_as_float((u).x & 0xFFFF0000u)) \
    PAIR(2, __uint_as_float((u).y << 16)) \
    PAIR(3, __uint_as_float((u).y & 0xFFFF0000u)) \
    PAIR(4, __uint_as_float((u).z << 16)) \
    PAIR(5, __uint_as_float((u).z & 0xFFFF0000u)) \
    PAIR(6, __uint_as_float((u).w << 16)) \
    PAIR(7, __uint_as_float((u).w & 0xFFFF0000u)) \
}

#define CONSUMEG4(R, g) \
    C1(R##0, hbase + ((g)*4+0)*8)  C1(R##1, hbase + ((g)*4+1)*8) \
    C1(R##2, hbase + ((g)*4+2)*8)  C1(R##3, hbase + ((g)*4+3)*8)

__global__ __launch_bounds__(512, 4)
void biaffine_loss(const float* __restrict__ EpG,
                   const ushort* __restrict__ haTb,
                   const float* __restrict__ Wout,
                   const int* __restrict__ ng,
                   const int* __restrict__ att,
                   const float* __restrict__ target,
                   float* __restrict__ out_logits,
                   float* __restrict__ accum,
                   float* __restrict__ out_loss)
{
    __shared__ float partial[PT][3][Ss];
    __shared__ float maskneg[PT][Ss];
    __shared__ float redmax[PT][2];
    __shared__ float red3[PT][2][3];
    __shared__ float swr_s;
    __shared__ __align__(16) float wS[Hh];
    __shared__ __align__(16) float e0S[Hh];
    __shared__ __align__(16) float e1S[Hh];

    // XCD-chunked bijective swizzle (NBLK=640, 8 XCDs, 80 blocks/XCD):
    // physical p -> logical L = (p%8)*80 + p/8; logical order is slab-major:
    // g = L/64 = b*Cc + c (one Ea slab), j = L%64 -> pt = b*64 + j.
    const int L   = ((int)blockIdx.x & 7) * 80 + ((int)blockIdx.x >> 3);
    const int g   = L >> 6;              // 0..9
    const int j   = L & 63;
    const int b   = (g >= Cc) ? 1 : 0;
    const int c   = g - b * Cc;
    const int bp0 = (b * 64 + j) * PT;
    const int tid = threadIdx.x;
    const int a   = tid & (Ss - 1);
    const int hq  = __builtin_amdgcn_readfirstlane(tid >> 7);   // 0..3, forced SGPR
    const int lane = tid & 63;

    const float* wrow = Wout + (size_t)c * Hh;
    const float* ep0  = EpG + (size_t)(bp0 + 0) * Hh;
    const float* ep1  = EpG + (size_t)(bp0 + 1) * Hh;

    if (tid < PT * Ss) {   // mask staging: unconditional ng loads (no att->ng chain)
        const int p_i = tid >> 7;
        const int aa  = tid & (Ss - 1);
        const int attv = att[b * Ss + aa];
        const int* ngp = ng + (size_t)(bp0 + p_i) * Cc * Ss + aa;
        const int n0 = ngp[0 * Ss], n1 = ngp[1 * Ss], n2 = ngp[2 * Ss],
                  n3 = ngp[3 * Ss], n4 = ngp[4 * Ss];
        const int any = (n0 | n1 | n2 | n3 | n4) & (attv > 0 ? -1 : 0);
        maskneg[p_i][aa] = any ? 0.0f : NEGV;
    }

    if (tid < 64) {    // wave 0: sumW[c] from global (coalesced)
        float s = 0.f;
        #pragma unroll
        for (int i = 0; i < Hh / 64; ++i) s += wrow[tid + i * 64];
        #pragma unroll
        for (int off = 32; off; off >>= 1) s += __shfl_xor(s, off, 64);
        if (tid == 0) swr_s = s;
    }

    // stage w / ep rows into LDS (coalesced, 9 KB total)
    for (int i = tid; i < Hh; i += 512) {
        wS[i]  = wrow[i];
        e0S[i] = ep0[i];
        e1S[i] = ep1[i];
    }

    // thread's Ea stream: uint4 j (8 h each); index = (hq*24 + j)*128 + a
    const uint4* hap4 = (const uint4*)(haTb + ((size_t)(b * Cc + c) * 96) * 1024)
                      + (size_t)hq * 24 * 128 + a;
    const int hbase = hq * 192;

    uint4 A0, A1, A2, A3;
    uint4 B0, B1, B2, B3;
    float ac00 = 0.f, ac01 = 0.f, ac10 = 0.f, ac11 = 0.f;

    LOADG4(A, 0)
    LOADG4(B, 1)
    __syncthreads();       // LDS w/ep ready; 8 global loads already in flight
    CONSUMEG4(A, 0)  LOADG4(A, 2)  SB
    CONSUMEG4(B, 1)  LOADG4(B, 3)  SB
    CONSUMEG4(A, 2)  LOADG4(A, 4)  SB
    CONSUMEG4(B, 3)  LOADG4(B, 5)  SB
    CONSUMEG4(A, 4)
    CONSUMEG4(B, 5)

    if (hq != 0) {
        partial[0][hq - 1][a] = ac00 + ac01;
        partial[1][hq - 1][a] = ac10 + ac11;
    }
    __syncthreads();

    float logit[PT];
    const int wv = tid >> 6;             // 0/1 for hq==0 threads
    if (hq == 0) {
        const float ps[PT] = { ac00 + ac01, ac10 + ac11 };
        #pragma unroll
        for (int p = 0; p < PT; ++p) {
            const float full = ps[p] + partial[p][0][a] + partial[p][1][a] + partial[p][2][a];
            logit[p] = swr_s - 2.0f * full + maskneg[p][a];
            out_logits[((size_t)(bp0 + p) * Cc + c) * Ss + a] = logit[p];
            float mx = logit[p];
            #pragma unroll
            for (int off = 32; off; off >>= 1) mx = fmaxf(mx, __shfl_xor(mx, off, 64));
            if (lane == 0) redmax[p][wv] = mx;
        }
    }
    __syncthreads();

    if (hq == 0) {
        #pragma unroll
        for (int p = 0; p < PT; ++p) {
            const float rm = fmaxf(redmax[p][0], redmax[p][1]);
            const float e  = __builtin_amdgcn_exp2f((logit[p] - rm) * 1.4426950408889634f);
            const float tg = target[((size_t)(bp0 + p) * Cc + c) * Ss + a];
            float se = e, st = tg, sx = tg * logit[p];
            #pragma unroll
            for (int off = 32; off; off >>= 1) {
                se += __shfl_xor(se, off, 64);
                st += __shfl_xor(st, off, 64);
                sx += __shfl_xor(sx, off, 64);
            }
            if (lane == 0) { red3[p][wv][0] = se; red3[p][wv][1] = st; red3[p][wv][2] = sx; }
        }
    }
    __syncthreads();

    if (tid == 0) {
        float nsum = 0.f, dsum = 0.f;
        #pragma unroll
        for (int p = 0; p < PT; ++p) {
            const float rm = fmaxf(redmax[p][0], redmax[p][1]);
            const float SE = red3[p][0][0] + red3[p][1][0];
            const float ST = red3[p][0][1] + red3[p][1][1];
            const float SX = red3[p][0][2] + red3[p][1][2];
            const float lse = rm + __builtin_amdgcn_logf(SE) * 0.6931471805599453f;
            nsum += lse * ST - SX;
            dsum += ST;
        }
        atomicAdd(&accum[0], nsum);
        atomicAdd(&accum[1], dsum);
        __threadfence();
        const unsigned old = atomicAdd((unsigned*)(accum + 2), 1u);
        if (old == (unsigned)(NBLK - 1)) {          // last block: finalize loss
            const float n = atomicAdd(&accum[0], 0.0f);
            const float d = atomicAdd(&accum[1], 0.0f);
            out_loss[0] = n / d;
        }
    }
}

extern "C" void kernel_launch(void* const* d_in, const int* in_sizes, int n_in,
                              void* d_out, int out_size, void* d_ws, size_t ws_size,
                              hipStream_t stream) {
    const float* seq    = (const float*)d_in[0];
    const int*   att    = (const int*)  d_in[1];
    const int*   ng     = (const int*)  d_in[2];
    const float* target = (const float*)d_in[3];
    const float* Wprd   = (const float*)d_in[4];
    const float* bprd   = (const float*)d_in[5];
    const float* Warg   = (const float*)d_in[6];
    const float* barg   = (const float*)d_in[7];
    const float* Wout   = (const float*)d_in[8];

    float*  out    = (float*)d_out;
    float*  EpG    = (float*)d_ws;                       // 196608 floats
    ushort* haTb   = (ushort*)(EpG + 196608);            // 983040 ushorts
    float*  accum  = EpG + 196608 + 491520;              // 3 slots

    gemm_mfma<<<dim3(4, 144), 256, 0, stream>>>(seq, Wprd, Warg, bprd, barg,
                                                EpG, haTb, accum);
    biaffine_loss<<<dim3(NBLK), 512, 0, stream>>>(EpG, haTb, Wout, ng, att, target,
                                                  out + 1, accum, out);
}

// Round 7
// 128.026 us; speedup vs baseline: 1.0018x; 1.0018x over previous
//
#include <hip/hip_runtime.h>
#include <math.h>

#define Bb 2
#define Ss 128
#define Hh 768
#define Cc 5
#define Mm 256       // Bb*Ss
#define NEGV -1024.0f
#define SCALE 2.8853900817779268f   // 2/ln(2): Ep*Ea = e^{2x}

// haTb: bf16 [b][c][h8][a][h&7], h8=h>>3 in [0,96)   -- stores Ea = exp2(scaled ha)
#define PT 2
#define NBLK (Mm / PT * Cc)   // 640

typedef __attribute__((ext_vector_type(8))) short bf16x8;
typedef __attribute__((ext_vector_type(4))) float f32x4;
typedef unsigned short ushort;

__device__ __forceinline__ unsigned pack_hi16(float hi, float lo) {
    return (__float_as_uint(hi) & 0xFFFF0000u) | (__float_as_uint(lo) >> 16);
}
__device__ __forceinline__ bf16x8 pack_bf16x8(float4 lo, float4 hi) {
    union { bf16x8 v; unsigned u[4]; } r;
    r.u[0] = pack_hi16(lo.y, lo.x);
    r.u[1] = pack_hi16(lo.w, lo.z);
    r.u[2] = pack_hi16(hi.y, hi.x);
    r.u[3] = pack_hi16(hi.w, hi.z);
    return r.v;
}
// round-to-nearest-even bf16 of f32
__device__ __forceinline__ ushort bf16_rne(float f) {
    unsigned b = __float_as_uint(f);
    return (ushort)((b + 0x7FFFu + ((b >> 16) & 1u)) >> 16);
}

#define SB __builtin_amdgcn_sched_barrier(0);

// ---------------- Kernel 1: LDS-staged bf16 MFMA GEMM (unchanged from R6) ----------------
__global__ __launch_bounds__(256)
void gemm_mfma(const float* __restrict__ X,
               const float* __restrict__ Wprd,
               const float* __restrict__ Warg,
               const float* __restrict__ bprd,
               const float* __restrict__ barg,
               float* __restrict__ EpG,
               ushort* __restrict__ haTb,
               float* __restrict__ accum)
{
    __shared__ __align__(16) ushort Asb[64][72];
    __shared__ __align__(16) ushort Bsb[32][72];

    if (blockIdx.x == 0 && blockIdx.y == 0 && threadIdx.x == 0) {
        accum[0] = 0.f; accum[1] = 0.f;
        ((unsigned*)accum)[2] = 0u;      // completion counter
    }
    const int bm   = blockIdx.x;          // 0..3   (64 rows)
    const int bn   = blockIdx.y;          // 0..143 (32 cols)
    const int tid  = threadIdx.x;
    const int wave = tid >> 6;
    const int lane = tid & 63;
    const int l16  = lane & 15;
    const int quad = lane >> 4;

    const float* Wsrc; const float* bsrc;
    const int nb = bn * 32;
    if (nb < Hh) { Wsrc = Wprd + (size_t)nb * Hh;        bsrc = bprd + nb; }
    else         { Wsrc = Warg + (size_t)(nb - Hh) * Hh; bsrc = barg + (nb - Hh); }

    const int srow = tid >> 2;
    const int sko  = (tid & 3) * 8;
    const float* gA = X + (size_t)(bm * 64 + srow) * Hh + sko;
    const float* gB = Wsrc + (size_t)(tid >> 2) * Hh + sko;   // valid for tid<128

    float4 a00 = *(const float4*)(gA);
    float4 a01 = *(const float4*)(gA + 4);
    float4 a10 = *(const float4*)(gA + 32);
    float4 a11 = *(const float4*)(gA + 36);
    float4 b00, b01, b10, b11;
    if (tid < 128) {
        b00 = *(const float4*)(gB);      b01 = *(const float4*)(gB + 4);
        b10 = *(const float4*)(gB + 32); b11 = *(const float4*)(gB + 36);
    }

    f32x4 acc0 = {0.f,0.f,0.f,0.f}, acc1 = {0.f,0.f,0.f,0.f};

    for (int k0 = 0; k0 < Hh; k0 += 64) {
        *(bf16x8*)&Asb[srow][sko]      = pack_bf16x8(a00, a01);
        *(bf16x8*)&Asb[srow][sko + 32] = pack_bf16x8(a10, a11);
        if (tid < 128) {
            *(bf16x8*)&Bsb[tid >> 2][sko]      = pack_bf16x8(b00, b01);
            *(bf16x8*)&Bsb[tid >> 2][sko + 32] = pack_bf16x8(b10, b11);
        }
        __syncthreads();
        if (k0 + 64 < Hh) {
            a00 = *(const float4*)(gA + k0 + 64);
            a01 = *(const float4*)(gA + k0 + 68);
            a10 = *(const float4*)(gA + k0 + 96);
            a11 = *(const float4*)(gA + k0 + 100);
            if (tid < 128) {
                b00 = *(const float4*)(gB + k0 + 64);
                b01 = *(const float4*)(gB + k0 + 68);
                b10 = *(const float4*)(gB + k0 + 96);
                b11 = *(const float4*)(gB + k0 + 100);
            }
        }
        {
            bf16x8 af0 = *(const bf16x8*)&Asb[wave * 16 + l16][quad * 8];
            bf16x8 c00 = *(const bf16x8*)&Bsb[l16][quad * 8];
            bf16x8 c10 = *(const bf16x8*)&Bsb[16 + l16][quad * 8];
            acc0 = __builtin_amdgcn_mfma_f32_16x16x32_bf16(af0, c00, acc0, 0, 0, 0);
            acc1 = __builtin_amdgcn_mfma_f32_16x16x32_bf16(af0, c10, acc1, 0, 0, 0);
            bf16x8 af1 = *(const bf16x8*)&Asb[wave * 16 + l16][quad * 8 + 32];
            bf16x8 c01 = *(const bf16x8*)&Bsb[l16][quad * 8 + 32];
            bf16x8 c11 = *(const bf16x8*)&Bsb[16 + l16][quad * 8 + 32];
            acc0 = __builtin_amdgcn_mfma_f32_16x16x32_bf16(af1, c01, acc0, 0, 0, 0);
            acc1 = __builtin_amdgcn_mfma_f32_16x16x32_bf16(af1, c11, acc1, 0, 0, 0);
        }
        __syncthreads();
    }

    const float sb0 = SCALE * bsrc[l16];
    const float sb1 = SCALE * bsrc[16 + l16];
    const int row = bm * 64 + wave * 16 + quad * 4;

    if (nb < Hh) {   // Ep: row-major fp32 [m][h] = exp2(hp')
        #pragma unroll
        for (int r = 0; r < 4; ++r) {
            const int mm = row + r;
            EpG[(size_t)mm * Hh + nb + l16]      = __builtin_amdgcn_exp2f(SCALE * acc0[r] + sb0);
            EpG[(size_t)mm * Hh + nb + 16 + l16] = __builtin_amdgcn_exp2f(SCALE * acc1[r] + sb1);
        }
    } else {         // Ea = exp2(ha') -> haTb bf16 [b][c][h>>3][a][h&7]
        const int q  = nb - Hh;
        const int cU = q / Hh;
        const int h0 = q % Hh;
        const int hA = h0 + l16;
        const int hB = h0 + 16 + l16;
        const size_t offA = (size_t)(hA >> 3) * 1024 + (hA & 7);
        const size_t offB = (size_t)(hB >> 3) * 1024 + (hB & 7);
        #pragma unroll
        for (int r = 0; r < 4; ++r) {
            const int mm = row + r;
            const int bI = mm >> 7, aI = mm & 127;
            const size_t base = ((size_t)(bI * Cc + cU) * 96) * 1024 + (size_t)aI * 8;
            const float e0 = __builtin_amdgcn_exp2f(SCALE * acc0[r] + sb0);
            const float e1 = __builtin_amdgcn_exp2f(SCALE * acc1[r] + sb1);
            haTb[base + offA] = bf16_rne(e0);
            haTb[base + offB] = bf16_rne(e1);
        }
    }
}

// ---------------- Kernel 2: biaffine ----------------
// R7 restructure (LDS-pipe-throughput attack):
//  - 8-way h-split: wave wvid owns h in [wvid*96, wvid*96+96) -- each broadcast
//    value is read by exactly ONE wave (was 2).
//  - each lane handles TWO a's (lane, lane+64): the two per-j C1s share one set
//    of broadcast reads -> broadcast b128 count per block halves (1152 -> 576).
//  - broadcast reads are explicit float4 (guaranteed ds_read_b128).
//  - single-wave butterfly epilogue (no redmax/red3 LDS dance, 2 fewer barriers).

#define LOADG4(R, g) \
    R##0 = hap4[(g)*256];       R##1 = hap4[(g)*256 + 64]; \
    R##2 = hap4[(g)*256 + 128]; R##3 = hap4[(g)*256 + 192];

// one h-term: 4 independent rcp chains (p0/p1 x a0/a1)
#define TERM(ww, q0, q1, ea0, ea1, A00, A01, A10, A11) { \
    float r; \
    r = __builtin_amdgcn_rcpf(fmaf((q0), (ea0), 1.0f)); A00 = fmaf((ww), r, A00); \
    r = __builtin_amdgcn_rcpf(fmaf((q1), (ea0), 1.0f)); A10 = fmaf((ww), r, A10); \
    r = __builtin_amdgcn_rcpf(fmaf((q0), (ea1), 1.0f)); A01 = fmaf((ww), r, A01); \
    r = __builtin_amdgcn_rcpf(fmaf((q1), (ea1), 1.0f)); A11 = fmaf((ww), r, A11); \
}

// one j (8 h) for both a's: 6 x ds_read_b128 broadcast + 8 TERMs
#define C2(uA, uB, hx_) { \
    const int hx = (hx_); \
    const float4 w4a = *(const float4*)&wS[hx];      \
    const float4 w4b = *(const float4*)&wS[hx + 4];  \
    const float4 q04a = *(const float4*)&e0S[hx];    \
    const float4 q04b = *(const float4*)&e0S[hx + 4];\
    const float4 q14a = *(const float4*)&e1S[hx];    \
    const float4 q14b = *(const float4*)&e1S[hx + 4];\
    TERM(w4a.x, q04a.x, q14a.x, __uint_as_float((uA).x << 16),         __uint_as_float((uB).x << 16),         acE00, acE01, acE10, acE11) \
    TERM(w4a.y, q04a.y, q14a.y, __uint_as_float((uA).x & 0xFFFF0000u), __uint_as_float((uB).x & 0xFFFF0000u), acO00, acO01, acO10, acO11) \
    TERM(w4a.z, q04a.z, q14a.z, __uint_as_float((uA).y << 16),         __uint_as_float((uB).y << 16),         acE00, acE01, acE10, acE11) \
    TERM(w4a.w, q04a.w, q14a.w, __uint_as_float((uA).y & 0xFFFF0000u), __uint_as_float((uB).y & 0xFFFF0000u), acO00, acO01, acO10, acO11) \
    TERM(w4b.x, q04b.x, q14b.x, __uint_as_float((uA).z << 16),         __uint_as_float((uB).z << 16),         acE00, acE01, acE10, acE11) \
    TERM(w4b.y, q04b.y, q14b.y, __uint_as_float((uA).z & 0xFFFF0000u), __uint_as_float((uB).z & 0xFFFF0000u), acO00, acO01, acO10, acO11) \
    TERM(w4b.z, q04b.z, q14b.z, __uint_as_float((uA).w << 16),         __uint_as_float((uB).w << 16),         acE00, acE01, acE10, acE11) \
    TERM(w4b.w, q04b.w, q14b.w, __uint_as_float((uA).w & 0xFFFF0000u), __uint_as_float((uB).w & 0xFFFF0000u), acO00, acO01, acO10, acO11) \
}

#define CONSUMEG(R, g) \
    C2(R##0, R##1, hq96 + ((g)*2 + 0) * 8) \
    C2(R##2, R##3, hq96 + ((g)*2 + 1) * 8)

__global__ __launch_bounds__(512, 4)
void biaffine_loss(const float* __restrict__ EpG,
                   const ushort* __restrict__ haTb,
                   const float* __restrict__ Wout,
                   const int* __restrict__ ng,
                   const int* __restrict__ att,
                   const float* __restrict__ target,
                   float* __restrict__ out_logits,
                   float* __restrict__ accum,
                   float* __restrict__ out_loss)
{
    __shared__ float partial[PT][7][Ss];
    __shared__ float maskneg[PT][Ss];
    __shared__ float swr_s;
    __shared__ __align__(16) float wS[Hh];
    __shared__ __align__(16) float e0S[Hh];
    __shared__ __align__(16) float e1S[Hh];

    // XCD-chunked bijective swizzle (NBLK=640, 8 XCDs, 80 blocks/XCD)
    const int L   = ((int)blockIdx.x & 7) * 80 + ((int)blockIdx.x >> 3);
    const int g   = L >> 6;              // 0..9
    const int j   = L & 63;
    const int b   = (g >= Cc) ? 1 : 0;
    const int c   = g - b * Cc;
    const int bp0 = (b * 64 + j) * PT;
    const int tid  = threadIdx.x;
    const int lane = tid & 63;
    const int wvid = __builtin_amdgcn_readfirstlane(tid >> 6);   // 0..7, SGPR
    const int hq96 = wvid * 96;

    const float* wrow = Wout + (size_t)c * Hh;
    const float* ep0  = EpG + (size_t)(bp0 + 0) * Hh;
    const float* ep1  = EpG + (size_t)(bp0 + 1) * Hh;

    if (tid < PT * Ss) {   // mask staging: unconditional ng loads
        const int p_i = tid >> 7;
        const int aa  = tid & (Ss - 1);
        const int attv = att[b * Ss + aa];
        const int* ngp = ng + (size_t)(bp0 + p_i) * Cc * Ss + aa;
        const int n0 = ngp[0 * Ss], n1 = ngp[1 * Ss], n2 = ngp[2 * Ss],
                  n3 = ngp[3 * Ss], n4 = ngp[4 * Ss];
        const int any = (n0 | n1 | n2 | n3 | n4) & (attv > 0 ? -1 : 0);
        maskneg[p_i][aa] = any ? 0.0f : NEGV;
    }

    if (tid < 64) {    // wave 0: sumW[c]
        float s = 0.f;
        #pragma unroll
        for (int i = 0; i < Hh / 64; ++i) s += wrow[tid + i * 64];
        #pragma unroll
        for (int off = 32; off; off >>= 1) s += __shfl_xor(s, off, 64);
        if (tid == 0) swr_s = s;
    }

    // stage w / ep rows into LDS (coalesced, 9 KB)
    for (int i = tid; i < Hh; i += 512) {
        wS[i]  = wrow[i];
        e0S[i] = ep0[i];
        e1S[i] = ep1[i];
    }

    // per-wave Ea stream: uint4 index = (wvid*12 + jj)*128 + a, a in {lane, lane+64}
    const uint4* hap4 = (const uint4*)(haTb + ((size_t)(b * Cc + c) * 96) * 1024)
                      + (size_t)wvid * 12 * 128 + lane;

    uint4 A0, A1, A2, A3;
    uint4 B0, B1, B2, B3;
    float acE00 = 0.f, acO00 = 0.f;   // p0, a0
    float acE01 = 0.f, acO01 = 0.f;   // p0, a1
    float acE10 = 0.f, acO10 = 0.f;   // p1, a0
    float acE11 = 0.f, acO11 = 0.f;   // p1, a1

    LOADG4(A, 0)
    LOADG4(B, 1)
    __syncthreads();       // LDS w/ep ready; 8 global loads already in flight
    CONSUMEG(A, 0)  LOADG4(A, 2)  SB
    CONSUMEG(B, 1)  LOADG4(B, 3)  SB
    CONSUMEG(A, 2)  LOADG4(A, 4)  SB
    CONSUMEG(B, 3)  LOADG4(B, 5)  SB
    CONSUMEG(A, 4)
    CONSUMEG(B, 5)

    if (wvid != 0) {
        partial[0][wvid - 1][lane]      = acE00 + acO00;
        partial[0][wvid - 1][lane + 64] = acE01 + acO01;
        partial[1][wvid - 1][lane]      = acE10 + acO10;
        partial[1][wvid - 1][lane + 64] = acE11 + acO11;
    }
    __syncthreads();

    if (wvid == 0) {
        float nsum = 0.f, dsum = 0.f;
        #pragma unroll
        for (int p = 0; p < PT; ++p) {
            float f0 = (p == 0) ? (acE00 + acO00) : (acE10 + acO10);
            float f1 = (p == 0) ? (acE01 + acO01) : (acE11 + acO11);
            #pragma unroll
            for (int k = 0; k < 7; ++k) {
                f0 += partial[p][k][lane];
                f1 += partial[p][k][lane + 64];
            }
            const float l0 = swr_s - 2.0f * f0 + maskneg[p][lane];
            const float l1 = swr_s - 2.0f * f1 + maskneg[p][lane + 64];
            const size_t obase = ((size_t)(bp0 + p) * Cc + c) * Ss;
            out_logits[obase + lane]      = l0;
            out_logits[obase + lane + 64] = l1;
            float mx = fmaxf(l0, l1);
            #pragma unroll
            for (int off = 32; off; off >>= 1) mx = fmaxf(mx, __shfl_xor(mx, off, 64));
            const float e = __builtin_amdgcn_exp2f((l0 - mx) * 1.4426950408889634f)
                          + __builtin_amdgcn_exp2f((l1 - mx) * 1.4426950408889634f);
            const float tg0 = target[obase + lane];
            const float tg1 = target[obase + lane + 64];
            float se = e, st = tg0 + tg1, sx = tg0 * l0 + tg1 * l1;
            #pragma unroll
            for (int off = 32; off; off >>= 1) {
                se += __shfl_xor(se, off, 64);
                st += __shfl_xor(st, off, 64);
                sx += __shfl_xor(sx, off, 64);
            }
            const float lse = mx + __builtin_amdgcn_logf(se) * 0.6931471805599453f;
            nsum += lse * st - sx;
            dsum += st;
        }
        if (lane == 0) {
            atomicAdd(&accum[0], nsum);
            atomicAdd(&accum[1], dsum);
            __threadfence();
            const unsigned old = atomicAdd((unsigned*)(accum + 2), 1u);
            if (old == (unsigned)(NBLK - 1)) {          // last block: finalize loss
                const float n = atomicAdd(&accum[0], 0.0f);
                const float d = atomicAdd(&accum[1], 0.0f);
                out_loss[0] = n / d;
            }
        }
    }
}

extern "C" void kernel_launch(void* const* d_in, const int* in_sizes, int n_in,
                              void* d_out, int out_size, void* d_ws, size_t ws_size,
                              hipStream_t stream) {
    const float* seq    = (const float*)d_in[0];
    const int*   att    = (const int*)  d_in[1];
    const int*   ng     = (const int*)  d_in[2];
    const float* target = (const float*)d_in[3];
    const float* Wprd   = (const float*)d_in[4];
    const float* bprd   = (const float*)d_in[5];
    const float* Warg   = (const float*)d_in[6];
    const float* barg   = (const float*)d_in[7];
    const float* Wout   = (const float*)d_in[8];

    float*  out    = (float*)d_out;
    float*  EpG    = (float*)d_ws;                       // 196608 floats
    ushort* haTb   = (ushort*)(EpG + 196608);            // 983040 ushorts
    float*  accum  = EpG + 196608 + 491520;              // 3 slots

    gemm_mfma<<<dim3(4, 144), 256, 0, stream>>>(seq, Wprd, Warg, bprd, barg,
                                                EpG, haTb, accum);
    biaffine_loss<<<dim3(NBLK), 512, 0, stream>>>(EpG, haTb, Wout, ng, att, target,
                                                  out + 1, accum, out);
}

// Round 8
// 114.252 us; speedup vs baseline: 1.1225x; 1.1206x over previous
//
#include <hip/hip_runtime.h>
#include <math.h>

#define Bb 2
#define Ss 128
#define Hh 768
#define Cc 5
#define Mm 256       // Bb*Ss
#define NEGV -1024.0f
#define SCALE 2.8853900817779268f   // 2/ln(2): Ep*Ea = e^{2x}

// haTb: bf16 [b][c][h8][a][h&7], h8=h>>3 in [0,96)   -- stores Ea = exp2(scaled ha)
#define PT 2
#define NBLK (Mm / PT * Cc)   // 640
#define NBUCKET 32           // loss-reduction buckets, 128B apart (32 floats)

typedef __attribute__((ext_vector_type(8))) short bf16x8;
typedef __attribute__((ext_vector_type(4))) float f32x4;
typedef unsigned short ushort;

__device__ __forceinline__ unsigned pack_hi16(float hi, float lo) {
    return (__float_as_uint(hi) & 0xFFFF0000u) | (__float_as_uint(lo) >> 16);
}
__device__ __forceinline__ bf16x8 pack_bf16x8(float4 lo, float4 hi) {
    union { bf16x8 v; unsigned u[4]; } r;
    r.u[0] = pack_hi16(lo.y, lo.x);
    r.u[1] = pack_hi16(lo.w, lo.z);
    r.u[2] = pack_hi16(hi.y, hi.x);
    r.u[3] = pack_hi16(hi.w, hi.z);
    return r.v;
}
// round-to-nearest-even bf16 of f32
__device__ __forceinline__ ushort bf16_rne(float f) {
    unsigned b = __float_as_uint(f);
    return (ushort)((b + 0x7FFFu + ((b >> 16) & 1u)) >> 16);
}

#define SB __builtin_amdgcn_sched_barrier(0);

// ---------------- Kernel 1: LDS-staged bf16 MFMA GEMM ----------------
__global__ __launch_bounds__(256)
void gemm_mfma(const float* __restrict__ X,
               const float* __restrict__ Wprd,
               const float* __restrict__ Warg,
               const float* __restrict__ bprd,
               const float* __restrict__ barg,
               float* __restrict__ EpG,
               ushort* __restrict__ haTb,
               float* __restrict__ accumArr)
{
    __shared__ __align__(16) ushort Asb[64][72];
    __shared__ __align__(16) ushort Bsb[32][72];

    if (blockIdx.x == 0 && blockIdx.y == 0) {   // zero the loss buckets
        for (int i = threadIdx.x; i < NBUCKET * 32; i += 256) accumArr[i] = 0.f;
    }
    const int bm   = blockIdx.x;          // 0..3   (64 rows)
    const int bn   = blockIdx.y;          // 0..143 (32 cols)
    const int tid  = threadIdx.x;
    const int wave = tid >> 6;
    const int lane = tid & 63;
    const int l16  = lane & 15;
    const int quad = lane >> 4;

    const float* Wsrc; const float* bsrc;
    const int nb = bn * 32;
    if (nb < Hh) { Wsrc = Wprd + (size_t)nb * Hh;        bsrc = bprd + nb; }
    else         { Wsrc = Warg + (size_t)(nb - Hh) * Hh; bsrc = barg + (nb - Hh); }

    const int srow = tid >> 2;
    const int sko  = (tid & 3) * 8;
    const float* gA = X + (size_t)(bm * 64 + srow) * Hh + sko;
    const float* gB = Wsrc + (size_t)(tid >> 2) * Hh + sko;   // valid for tid<128

    float4 a00 = *(const float4*)(gA);
    float4 a01 = *(const float4*)(gA + 4);
    float4 a10 = *(const float4*)(gA + 32);
    float4 a11 = *(const float4*)(gA + 36);
    float4 b00, b01, b10, b11;
    if (tid < 128) {
        b00 = *(const float4*)(gB);      b01 = *(const float4*)(gB + 4);
        b10 = *(const float4*)(gB + 32); b11 = *(const float4*)(gB + 36);
    }

    f32x4 acc0 = {0.f,0.f,0.f,0.f}, acc1 = {0.f,0.f,0.f,0.f};

    for (int k0 = 0; k0 < Hh; k0 += 64) {
        *(bf16x8*)&Asb[srow][sko]      = pack_bf16x8(a00, a01);
        *(bf16x8*)&Asb[srow][sko + 32] = pack_bf16x8(a10, a11);
        if (tid < 128) {
            *(bf16x8*)&Bsb[tid >> 2][sko]      = pack_bf16x8(b00, b01);
            *(bf16x8*)&Bsb[tid >> 2][sko + 32] = pack_bf16x8(b10, b11);
        }
        __syncthreads();
        if (k0 + 64 < Hh) {
            a00 = *(const float4*)(gA + k0 + 64);
            a01 = *(const float4*)(gA + k0 + 68);
            a10 = *(const float4*)(gA + k0 + 96);
            a11 = *(const float4*)(gA + k0 + 100);
            if (tid < 128) {
                b00 = *(const float4*)(gB + k0 + 64);
                b01 = *(const float4*)(gB + k0 + 68);
                b10 = *(const float4*)(gB + k0 + 96);
                b11 = *(const float4*)(gB + k0 + 100);
            }
        }
        {
            bf16x8 af0 = *(const bf16x8*)&Asb[wave * 16 + l16][quad * 8];
            bf16x8 c00 = *(const bf16x8*)&Bsb[l16][quad * 8];
            bf16x8 c10 = *(const bf16x8*)&Bsb[16 + l16][quad * 8];
            acc0 = __builtin_amdgcn_mfma_f32_16x16x32_bf16(af0, c00, acc0, 0, 0, 0);
            acc1 = __builtin_amdgcn_mfma_f32_16x16x32_bf16(af0, c10, acc1, 0, 0, 0);
            bf16x8 af1 = *(const bf16x8*)&Asb[wave * 16 + l16][quad * 8 + 32];
            bf16x8 c01 = *(const bf16x8*)&Bsb[l16][quad * 8 + 32];
            bf16x8 c11 = *(const bf16x8*)&Bsb[16 + l16][quad * 8 + 32];
            acc0 = __builtin_amdgcn_mfma_f32_16x16x32_bf16(af1, c01, acc0, 0, 0, 0);
            acc1 = __builtin_amdgcn_mfma_f32_16x16x32_bf16(af1, c11, acc1, 0, 0, 0);
        }
        __syncthreads();
    }

    const float sb0 = SCALE * bsrc[l16];
    const float sb1 = SCALE * bsrc[16 + l16];
    const int row = bm * 64 + wave * 16 + quad * 4;

    if (nb < Hh) {   // Ep: row-major fp32 [m][h] = exp2(hp')
        #pragma unroll
        for (int r = 0; r < 4; ++r) {
            const int mm = row + r;
            EpG[(size_t)mm * Hh + nb + l16]      = __builtin_amdgcn_exp2f(SCALE * acc0[r] + sb0);
            EpG[(size_t)mm * Hh + nb + 16 + l16] = __builtin_amdgcn_exp2f(SCALE * acc1[r] + sb1);
        }
    } else {         // Ea = exp2(ha') -> haTb bf16 [b][c][h>>3][a][h&7]
        const int q  = nb - Hh;
        const int cU = q / Hh;
        const int h0 = q % Hh;
        const int hA = h0 + l16;
        const int hB = h0 + 16 + l16;
        const size_t offA = (size_t)(hA >> 3) * 1024 + (hA & 7);
        const size_t offB = (size_t)(hB >> 3) * 1024 + (hB & 7);
        #pragma unroll
        for (int r = 0; r < 4; ++r) {
            const int mm = row + r;
            const int bI = mm >> 7, aI = mm & 127;
            const size_t base = ((size_t)(bI * Cc + cU) * 96) * 1024 + (size_t)aI * 8;
            const float e0 = __builtin_amdgcn_exp2f(SCALE * acc0[r] + sb0);
            const float e1 = __builtin_amdgcn_exp2f(SCALE * acc1[r] + sb1);
            haTb[base + offA] = bf16_rne(e0);
            haTb[base + offB] = bf16_rne(e1);
        }
    }
}

// ---------------- Kernel 2: biaffine ----------------
// Main loop identical to R7 (8-way h-split, lane-pair a's, float4 LDS broadcast).
// R8 change: epilogue loss reduction is BUCKETED FIRE-AND-FORGET -- 32 buckets
// on distinct 128B lines, no returning atomic, no __threadfence, no completion
// counter. The old single-line {2 atomics + fence + returning RMW} x 640 blocks
// serialized at the device coherence point (~40us floor, invariant across five
// compute restructures R0-R7). Final n/d moved to a 1-block kernel.

#define LOADG4(R, g) \
    R##0 = hap4[(g)*256];       R##1 = hap4[(g)*256 + 64]; \
    R##2 = hap4[(g)*256 + 128]; R##3 = hap4[(g)*256 + 192];

#define TERM(ww, q0, q1, ea0, ea1, A00, A01, A10, A11) { \
    float r; \
    r = __builtin_amdgcn_rcpf(fmaf((q0), (ea0), 1.0f)); A00 = fmaf((ww), r, A00); \
    r = __builtin_amdgcn_rcpf(fmaf((q1), (ea0), 1.0f)); A10 = fmaf((ww), r, A10); \
    r = __builtin_amdgcn_rcpf(fmaf((q0), (ea1), 1.0f)); A01 = fmaf((ww), r, A01); \
    r = __builtin_amdgcn_rcpf(fmaf((q1), (ea1), 1.0f)); A11 = fmaf((ww), r, A11); \
}

#define C2(uA, uB, hx_) { \
    const int hx = (hx_); \
    const float4 w4a = *(const float4*)&wS[hx];      \
    const float4 w4b = *(const float4*)&wS[hx + 4];  \
    const float4 q04a = *(const float4*)&e0S[hx];    \
    const float4 q04b = *(const float4*)&e0S[hx + 4];\
    const float4 q14a = *(const float4*)&e1S[hx];    \
    const float4 q14b = *(const float4*)&e1S[hx + 4];\
    TERM(w4a.x, q04a.x, q14a.x, __uint_as_float((uA).x << 16),         __uint_as_float((uB).x << 16),         acE00, acE01, acE10, acE11) \
    TERM(w4a.y, q04a.y, q14a.y, __uint_as_float((uA).x & 0xFFFF0000u), __uint_as_float((uB).x & 0xFFFF0000u), acO00, acO01, acO10, acO11) \
    TERM(w4a.z, q04a.z, q14a.z, __uint_as_float((uA).y << 16),         __uint_as_float((uB).y << 16),         acE00, acE01, acE10, acE11) \
    TERM(w4a.w, q04a.w, q14a.w, __uint_as_float((uA).y & 0xFFFF0000u), __uint_as_float((uB).y & 0xFFFF0000u), acO00, acO01, acO10, acO11) \
    TERM(w4b.x, q04b.x, q14b.x, __uint_as_float((uA).z << 16),         __uint_as_float((uB).z << 16),         acE00, acE01, acE10, acE11) \
    TERM(w4b.y, q04b.y, q14b.y, __uint_as_float((uA).z & 0xFFFF0000u), __uint_as_float((uB).z & 0xFFFF0000u), acO00, acO01, acO10, acO11) \
    TERM(w4b.z, q04b.z, q14b.z, __uint_as_float((uA).w << 16),         __uint_as_float((uB).w << 16),         acE00, acE01, acE10, acE11) \
    TERM(w4b.w, q04b.w, q14b.w, __uint_as_float((uA).w & 0xFFFF0000u), __uint_as_float((uB).w & 0xFFFF0000u), acO00, acO01, acO10, acO11) \
}

#define CONSUMEG(R, g) \
    C2(R##0, R##1, hq96 + ((g)*2 + 0) * 8) \
    C2(R##2, R##3, hq96 + ((g)*2 + 1) * 8)

__global__ __launch_bounds__(512, 4)
void biaffine_loss(const float* __restrict__ EpG,
                   const ushort* __restrict__ haTb,
                   const float* __restrict__ Wout,
                   const int* __restrict__ ng,
                   const int* __restrict__ att,
                   const float* __restrict__ target,
                   float* __restrict__ out_logits,
                   float* __restrict__ accumArr)
{
    __shared__ float partial[PT][7][Ss];
    __shared__ float maskneg[PT][Ss];
    __shared__ float swr_s;
    __shared__ __align__(16) float wS[Hh];
    __shared__ __align__(16) float e0S[Hh];
    __shared__ __align__(16) float e1S[Hh];

    // XCD-chunked bijective swizzle (NBLK=640, 8 XCDs, 80 blocks/XCD)
    const int L   = ((int)blockIdx.x & 7) * 80 + ((int)blockIdx.x >> 3);
    const int g   = L >> 6;              // 0..9
    const int j   = L & 63;
    const int b   = (g >= Cc) ? 1 : 0;
    const int c   = g - b * Cc;
    const int bp0 = (b * 64 + j) * PT;
    const int tid  = threadIdx.x;
    const int lane = tid & 63;
    const int wvid = __builtin_amdgcn_readfirstlane(tid >> 6);   // 0..7, SGPR
    const int hq96 = wvid * 96;

    const float* wrow = Wout + (size_t)c * Hh;
    const float* ep0  = EpG + (size_t)(bp0 + 0) * Hh;
    const float* ep1  = EpG + (size_t)(bp0 + 1) * Hh;

    if (tid < PT * Ss) {   // mask staging: unconditional ng loads
        const int p_i = tid >> 7;
        const int aa  = tid & (Ss - 1);
        const int attv = att[b * Ss + aa];
        const int* ngp = ng + (size_t)(bp0 + p_i) * Cc * Ss + aa;
        const int n0 = ngp[0 * Ss], n1 = ngp[1 * Ss], n2 = ngp[2 * Ss],
                  n3 = ngp[3 * Ss], n4 = ngp[4 * Ss];
        const int any = (n0 | n1 | n2 | n3 | n4) & (attv > 0 ? -1 : 0);
        maskneg[p_i][aa] = any ? 0.0f : NEGV;
    }

    if (tid < 64) {    // wave 0: sumW[c]
        float s = 0.f;
        #pragma unroll
        for (int i = 0; i < Hh / 64; ++i) s += wrow[tid + i * 64];
        #pragma unroll
        for (int off = 32; off; off >>= 1) s += __shfl_xor(s, off, 64);
        if (tid == 0) swr_s = s;
    }

    // stage w / ep rows into LDS (coalesced, 9 KB)
    for (int i = tid; i < Hh; i += 512) {
        wS[i]  = wrow[i];
        e0S[i] = ep0[i];
        e1S[i] = ep1[i];
    }

    // per-wave Ea stream: uint4 index = (wvid*12 + jj)*128 + a, a in {lane, lane+64}
    const uint4* hap4 = (const uint4*)(haTb + ((size_t)(b * Cc + c) * 96) * 1024)
                      + (size_t)wvid * 12 * 128 + lane;

    uint4 A0, A1, A2, A3;
    uint4 B0, B1, B2, B3;
    float acE00 = 0.f, acO00 = 0.f;   // p0, a0
    float acE01 = 0.f, acO01 = 0.f;   // p0, a1
    float acE10 = 0.f, acO10 = 0.f;   // p1, a0
    float acE11 = 0.f, acO11 = 0.f;   // p1, a1

    LOADG4(A, 0)
    LOADG4(B, 1)
    __syncthreads();       // LDS w/ep ready; 8 global loads already in flight
    CONSUMEG(A, 0)  LOADG4(A, 2)  SB
    CONSUMEG(B, 1)  LOADG4(B, 3)  SB
    CONSUMEG(A, 2)  LOADG4(A, 4)  SB
    CONSUMEG(B, 3)  LOADG4(B, 5)  SB
    CONSUMEG(A, 4)
    CONSUMEG(B, 5)

    if (wvid != 0) {
        partial[0][wvid - 1][lane]      = acE00 + acO00;
        partial[0][wvid - 1][lane + 64] = acE01 + acO01;
        partial[1][wvid - 1][lane]      = acE10 + acO10;
        partial[1][wvid - 1][lane + 64] = acE11 + acO11;
    }
    __syncthreads();

    if (wvid == 0) {
        float nsum = 0.f, dsum = 0.f;
        #pragma unroll
        for (int p = 0; p < PT; ++p) {
            float f0 = (p == 0) ? (acE00 + acO00) : (acE10 + acO10);
            float f1 = (p == 0) ? (acE01 + acO01) : (acE11 + acO11);
            #pragma unroll
            for (int k = 0; k < 7; ++k) {
                f0 += partial[p][k][lane];
                f1 += partial[p][k][lane + 64];
            }
            const float l0 = swr_s - 2.0f * f0 + maskneg[p][lane];
            const float l1 = swr_s - 2.0f * f1 + maskneg[p][lane + 64];
            const size_t obase = ((size_t)(bp0 + p) * Cc + c) * Ss;
            out_logits[obase + lane]      = l0;
            out_logits[obase + lane + 64] = l1;
            float mx = fmaxf(l0, l1);
            #pragma unroll
            for (int off = 32; off; off >>= 1) mx = fmaxf(mx, __shfl_xor(mx, off, 64));
            const float e = __builtin_amdgcn_exp2f((l0 - mx) * 1.4426950408889634f)
                          + __builtin_amdgcn_exp2f((l1 - mx) * 1.4426950408889634f);
            const float tg0 = target[obase + lane];
            const float tg1 = target[obase + lane + 64];
            float se = e, st = tg0 + tg1, sx = tg0 * l0 + tg1 * l1;
            #pragma unroll
            for (int off = 32; off; off >>= 1) {
                se += __shfl_xor(se, off, 64);
                st += __shfl_xor(st, off, 64);
                sx += __shfl_xor(sx, off, 64);
            }
            const float lse = mx + __builtin_amdgcn_logf(se) * 0.6931471805599453f;
            nsum += lse * st - sx;
            dsum += st;
        }
        if (lane == 0) {   // bucketed fire-and-forget: no fence, no counter
            const int bkt = ((int)blockIdx.x & (NBUCKET - 1)) * 32;
            atomicAdd(&accumArr[bkt],     nsum);
            atomicAdd(&accumArr[bkt + 1], dsum);
        }
    }
}

// ---------------- Kernel 3: finalize (1 block, 64 thr) ----------------
__global__ __launch_bounds__(64)
void finalize_loss(const float* __restrict__ accumArr,
                   float* __restrict__ out_loss)
{
    const int lane = threadIdx.x;
    float n = 0.f, d = 0.f;
    if (lane < NBUCKET) { n = accumArr[lane * 32]; d = accumArr[lane * 32 + 1]; }
    #pragma unroll
    for (int off = 32; off; off >>= 1) {
        n += __shfl_xor(n, off, 64);
        d += __shfl_xor(d, off, 64);
    }
    if (lane == 0) out_loss[0] = n / d;
}

extern "C" void kernel_launch(void* const* d_in, const int* in_sizes, int n_in,
                              void* d_out, int out_size, void* d_ws, size_t ws_size,
                              hipStream_t stream) {
    const float* seq    = (const float*)d_in[0];
    const int*   att    = (const int*)  d_in[1];
    const int*   ng     = (const int*)  d_in[2];
    const float* target = (const float*)d_in[3];
    const float* Wprd   = (const float*)d_in[4];
    const float* bprd   = (const float*)d_in[5];
    const float* Warg   = (const float*)d_in[6];
    const float* barg   = (const float*)d_in[7];
    const float* Wout   = (const float*)d_in[8];

    float*  out      = (float*)d_out;
    float*  EpG      = (float*)d_ws;                     // 196608 floats
    ushort* haTb     = (ushort*)(EpG + 196608);          // 983040 ushorts
    float*  accumArr = EpG + 196608 + 491520;            // 1024 floats (32 buckets x 128B)

    gemm_mfma<<<dim3(4, 144), 256, 0, stream>>>(seq, Wprd, Warg, bprd, barg,
                                                EpG, haTb, accumArr);
    biaffine_loss<<<dim3(NBLK), 512, 0, stream>>>(EpG, haTb, Wout, ng, att, target,
                                                  out + 1, accumArr);
    finalize_loss<<<1, 64, 0, stream>>>(accumArr, out);
}

// Round 9
// 112.168 us; speedup vs baseline: 1.1434x; 1.0186x over previous
//
#include <hip/hip_runtime.h>
#include <math.h>

#define Bb 2
#define Ss 128
#define Hh 768
#define Cc 5
#define Mm 256       // Bb*Ss
#define NEGV -1024.0f
#define SCALE 2.8853900817779268f   // 2/ln(2): Ep*Ea = e^{2x}

// haTb: bf16 [b][c][h8][a][h&7], h8=h>>3 in [0,96)   -- stores Ea = exp2(scaled ha)
#define PT 2
#define NBLK (Mm / PT * Cc)   // 640
#define NBUCKET 32           // loss-reduction buckets, 128B apart (32 floats)

typedef __attribute__((ext_vector_type(8))) short bf16x8;
typedef __attribute__((ext_vector_type(4))) float f32x4;
typedef unsigned short ushort;

__device__ __forceinline__ unsigned pack_hi16(float hi, float lo) {
    return (__float_as_uint(hi) & 0xFFFF0000u) | (__float_as_uint(lo) >> 16);
}
__device__ __forceinline__ bf16x8 pack_bf16x8(float4 lo, float4 hi) {
    union { bf16x8 v; unsigned u[4]; } r;
    r.u[0] = pack_hi16(lo.y, lo.x);
    r.u[1] = pack_hi16(lo.w, lo.z);
    r.u[2] = pack_hi16(hi.y, hi.x);
    r.u[3] = pack_hi16(hi.w, hi.z);
    return r.v;
}
// round-to-nearest-even bf16 of f32
__device__ __forceinline__ ushort bf16_rne(float f) {
    unsigned b = __float_as_uint(f);
    return (ushort)((b + 0x7FFFu + ((b >> 16) & 1u)) >> 16);
}

#define SB __builtin_amdgcn_sched_barrier(0);

// ---------------- Kernel 1: LDS-staged bf16 MFMA GEMM ----------------
// R9: grid swapped to (bn, bm) = (144, 4). The 4 blocks sharing one W-tile are
// now ids {bn, 144+bn, 288+bn, 432+bn}; 144%8==0 so all land on the SAME XCD ->
// W-tile fetched into one L2 instead of four (W L3->L2 traffic 56 -> 14 MB).
__global__ __launch_bounds__(256)
void gemm_mfma(const float* __restrict__ X,
               const float* __restrict__ Wprd,
               const float* __restrict__ Warg,
               const float* __restrict__ bprd,
               const float* __restrict__ barg,
               float* __restrict__ EpG,
               ushort* __restrict__ haTb,
               float* __restrict__ accumArr)
{
    __shared__ __align__(16) ushort Asb[64][72];
    __shared__ __align__(16) ushort Bsb[32][72];

    if (blockIdx.x == 0 && blockIdx.y == 0) {   // zero the loss buckets
        for (int i = threadIdx.x; i < NBUCKET * 32; i += 256) accumArr[i] = 0.f;
    }
    const int bn   = blockIdx.x;          // 0..143 (32 cols)
    const int bm   = blockIdx.y;          // 0..3   (64 rows)
    const int tid  = threadIdx.x;
    const int wave = tid >> 6;
    const int lane = tid & 63;
    const int l16  = lane & 15;
    const int quad = lane >> 4;

    const float* Wsrc; const float* bsrc;
    const int nb = bn * 32;
    if (nb < Hh) { Wsrc = Wprd + (size_t)nb * Hh;        bsrc = bprd + nb; }
    else         { Wsrc = Warg + (size_t)(nb - Hh) * Hh; bsrc = barg + (nb - Hh); }

    const int srow = tid >> 2;
    const int sko  = (tid & 3) * 8;
    const float* gA = X + (size_t)(bm * 64 + srow) * Hh + sko;
    const float* gB = Wsrc + (size_t)(tid >> 2) * Hh + sko;   // valid for tid<128

    float4 a00 = *(const float4*)(gA);
    float4 a01 = *(const float4*)(gA + 4);
    float4 a10 = *(const float4*)(gA + 32);
    float4 a11 = *(const float4*)(gA + 36);
    float4 b00, b01, b10, b11;
    if (tid < 128) {
        b00 = *(const float4*)(gB);      b01 = *(const float4*)(gB + 4);
        b10 = *(const float4*)(gB + 32); b11 = *(const float4*)(gB + 36);
    }

    f32x4 acc0 = {0.f,0.f,0.f,0.f}, acc1 = {0.f,0.f,0.f,0.f};

    for (int k0 = 0; k0 < Hh; k0 += 64) {
        *(bf16x8*)&Asb[srow][sko]      = pack_bf16x8(a00, a01);
        *(bf16x8*)&Asb[srow][sko + 32] = pack_bf16x8(a10, a11);
        if (tid < 128) {
            *(bf16x8*)&Bsb[tid >> 2][sko]      = pack_bf16x8(b00, b01);
            *(bf16x8*)&Bsb[tid >> 2][sko + 32] = pack_bf16x8(b10, b11);
        }
        __syncthreads();
        if (k0 + 64 < Hh) {
            a00 = *(const float4*)(gA + k0 + 64);
            a01 = *(const float4*)(gA + k0 + 68);
            a10 = *(const float4*)(gA + k0 + 96);
            a11 = *(const float4*)(gA + k0 + 100);
            if (tid < 128) {
                b00 = *(const float4*)(gB + k0 + 64);
                b01 = *(const float4*)(gB + k0 + 68);
                b10 = *(const float4*)(gB + k0 + 96);
                b11 = *(const float4*)(gB + k0 + 100);
            }
        }
        {
            bf16x8 af0 = *(const bf16x8*)&Asb[wave * 16 + l16][quad * 8];
            bf16x8 c00 = *(const bf16x8*)&Bsb[l16][quad * 8];
            bf16x8 c10 = *(const bf16x8*)&Bsb[16 + l16][quad * 8];
            acc0 = __builtin_amdgcn_mfma_f32_16x16x32_bf16(af0, c00, acc0, 0, 0, 0);
            acc1 = __builtin_amdgcn_mfma_f32_16x16x32_bf16(af0, c10, acc1, 0, 0, 0);
            bf16x8 af1 = *(const bf16x8*)&Asb[wave * 16 + l16][quad * 8 + 32];
            bf16x8 c01 = *(const bf16x8*)&Bsb[l16][quad * 8 + 32];
            bf16x8 c11 = *(const bf16x8*)&Bsb[16 + l16][quad * 8 + 32];
            acc0 = __builtin_amdgcn_mfma_f32_16x16x32_bf16(af1, c01, acc0, 0, 0, 0);
            acc1 = __builtin_amdgcn_mfma_f32_16x16x32_bf16(af1, c11, acc1, 0, 0, 0);
        }
        __syncthreads();
    }

    const float sb0 = SCALE * bsrc[l16];
    const float sb1 = SCALE * bsrc[16 + l16];
    const int row = bm * 64 + wave * 16 + quad * 4;

    if (nb < Hh) {   // Ep: row-major fp32 [m][h] = exp2(hp')
        #pragma unroll
        for (int r = 0; r < 4; ++r) {
            const int mm = row + r;
            EpG[(size_t)mm * Hh + nb + l16]      = __builtin_amdgcn_exp2f(SCALE * acc0[r] + sb0);
            EpG[(size_t)mm * Hh + nb + 16 + l16] = __builtin_amdgcn_exp2f(SCALE * acc1[r] + sb1);
        }
    } else {         // Ea = exp2(ha') -> haTb bf16 [b][c][h>>3][a][h&7]
        const int q  = nb - Hh;
        const int cU = q / Hh;
        const int h0 = q % Hh;
        const int hA = h0 + l16;
        const int hB = h0 + 16 + l16;
        const size_t offA = (size_t)(hA >> 3) * 1024 + (hA & 7);
        const size_t offB = (size_t)(hB >> 3) * 1024 + (hB & 7);
        #pragma unroll
        for (int r = 0; r < 4; ++r) {
            const int mm = row + r;
            const int bI = mm >> 7, aI = mm & 127;
            const size_t base = ((size_t)(bI * Cc + cU) * 96) * 1024 + (size_t)aI * 8;
            const float e0 = __builtin_amdgcn_exp2f(SCALE * acc0[r] + sb0);
            const float e1 = __builtin_amdgcn_exp2f(SCALE * acc1[r] + sb1);
            haTb[base + offA] = bf16_rne(e0);
            haTb[base + offB] = bf16_rne(e1);
        }
    }
}

// ---------------- Kernel 2: biaffine ----------------
// Main loop identical to R8. R9 changes (latency-exposure trims):
//  - mask is IN-REGISTER: waves 0-1 issue att/ng loads AFTER the staging
//    barrier (hidden under the main loop), consume at epilogue. maskneg LDS
//    and its prologue chain deleted.
//  - sumW moved to wave 2, post-barrier, reading staged wS from LDS.
//  - all 8 waves write partial[p][wvid]; epilogue split: wave0->p0, wave1->p1
//    (target loads issued first). Logit add-order preserved -> bit-identical.

#define LOADG4(R, g) \
    R##0 = hap4[(g)*256];       R##1 = hap4[(g)*256 + 64]; \
    R##2 = hap4[(g)*256 + 128]; R##3 = hap4[(g)*256 + 192];

#define TERM(ww, q0, q1, ea0, ea1, A00, A01, A10, A11) { \
    float r; \
    r = __builtin_amdgcn_rcpf(fmaf((q0), (ea0), 1.0f)); A00 = fmaf((ww), r, A00); \
    r = __builtin_amdgcn_rcpf(fmaf((q1), (ea0), 1.0f)); A10 = fmaf((ww), r, A10); \
    r = __builtin_amdgcn_rcpf(fmaf((q0), (ea1), 1.0f)); A01 = fmaf((ww), r, A01); \
    r = __builtin_amdgcn_rcpf(fmaf((q1), (ea1), 1.0f)); A11 = fmaf((ww), r, A11); \
}

#define C2(uA, uB, hx_) { \
    const int hx = (hx_); \
    const float4 w4a = *(const float4*)&wS[hx];      \
    const float4 w4b = *(const float4*)&wS[hx + 4];  \
    const float4 q04a = *(const float4*)&e0S[hx];    \
    const float4 q04b = *(const float4*)&e0S[hx + 4];\
    const float4 q14a = *(const float4*)&e1S[hx];    \
    const float4 q14b = *(const float4*)&e1S[hx + 4];\
    TERM(w4a.x, q04a.x, q14a.x, __uint_as_float((uA).x << 16),         __uint_as_float((uB).x << 16),         acE00, acE01, acE10, acE11) \
    TERM(w4a.y, q04a.y, q14a.y, __uint_as_float((uA).x & 0xFFFF0000u), __uint_as_float((uB).x & 0xFFFF0000u), acO00, acO01, acO10, acO11) \
    TERM(w4a.z, q04a.z, q14a.z, __uint_as_float((uA).y << 16),         __uint_as_float((uB).y << 16),         acE00, acE01, acE10, acE11) \
    TERM(w4a.w, q04a.w, q14a.w, __uint_as_float((uA).y & 0xFFFF0000u), __uint_as_float((uB).y & 0xFFFF0000u), acO00, acO01, acO10, acO11) \
    TERM(w4b.x, q04b.x, q14b.x, __uint_as_float((uA).z << 16),         __uint_as_float((uB).z << 16),         acE00, acE01, acE10, acE11) \
    TERM(w4b.y, q04b.y, q14b.y, __uint_as_float((uA).z & 0xFFFF0000u), __uint_as_float((uB).z & 0xFFFF0000u), acO00, acO01, acO10, acO11) \
    TERM(w4b.z, q04b.z, q14b.z, __uint_as_float((uA).w << 16),         __uint_as_float((uB).w << 16),         acE00, acE01, acE10, acE11) \
    TERM(w4b.w, q04b.w, q14b.w, __uint_as_float((uA).w & 0xFFFF0000u), __uint_as_float((uB).w & 0xFFFF0000u), acO00, acO01, acO10, acO11) \
}

#define CONSUMEG(R, g) \
    C2(R##0, R##1, hq96 + ((g)*2 + 0) * 8) \
    C2(R##2, R##3, hq96 + ((g)*2 + 1) * 8)

__global__ __launch_bounds__(512, 4)
void biaffine_loss(const float* __restrict__ EpG,
                   const ushort* __restrict__ haTb,
                   const float* __restrict__ Wout,
                   const int* __restrict__ ng,
                   const int* __restrict__ att,
                   const float* __restrict__ target,
                   float* __restrict__ out_logits,
                   float* __restrict__ accumArr)
{
    __shared__ float partial[PT][8][Ss];
    __shared__ float swr_s;
    __shared__ __align__(16) float wS[Hh];
    __shared__ __align__(16) float e0S[Hh];
    __shared__ __align__(16) float e1S[Hh];

    // XCD-chunked bijective swizzle (NBLK=640, 8 XCDs, 80 blocks/XCD)
    const int L   = ((int)blockIdx.x & 7) * 80 + ((int)blockIdx.x >> 3);
    const int g   = L >> 6;              // 0..9
    const int j   = L & 63;
    const int b   = (g >= Cc) ? 1 : 0;
    const int c   = g - b * Cc;
    const int bp0 = (b * 64 + j) * PT;
    const int tid  = threadIdx.x;
    const int lane = tid & 63;
    const int wvid = __builtin_amdgcn_readfirstlane(tid >> 6);   // 0..7, SGPR
    const int hq96 = wvid * 96;

    const float* wrow = Wout + (size_t)c * Hh;
    const float* ep0  = EpG + (size_t)(bp0 + 0) * Hh;
    const float* ep1  = EpG + (size_t)(bp0 + 1) * Hh;

    // stage w / ep rows into LDS (the ONLY pre-barrier work)
    for (int i = tid; i < Hh; i += 512) {
        wS[i]  = wrow[i];
        e0S[i] = ep0[i];
        e1S[i] = ep1[i];
    }

    // per-wave Ea stream: uint4 index = (wvid*12 + jj)*128 + a, a in {lane, lane+64}
    const uint4* hap4 = (const uint4*)(haTb + ((size_t)(b * Cc + c) * 96) * 1024)
                      + (size_t)wvid * 12 * 128 + lane;

    uint4 A0, A1, A2, A3;
    uint4 B0, B1, B2, B3;
    float acE00 = 0.f, acO00 = 0.f;   // p0, a0
    float acE01 = 0.f, acO01 = 0.f;   // p0, a1
    float acE10 = 0.f, acO10 = 0.f;   // p1, a0
    float acE11 = 0.f, acO11 = 0.f;   // p1, a1

    LOADG4(A, 0)
    LOADG4(B, 1)
    __syncthreads();       // LDS w/ep ready; 8 global loads already in flight

    // post-barrier wave-role prologue (latency hides under the main loop)
    int attv0 = 0, attv1 = 0;
    int ngA0 = 0, ngA1 = 0, ngA2 = 0, ngA3 = 0, ngA4 = 0;
    int ngB0 = 0, ngB1 = 0, ngB2 = 0, ngB3 = 0, ngB4 = 0;
    if (wvid < 2) {        // mask inputs for p = wvid, a in {lane, lane+64}
        attv0 = att[b * Ss + lane];
        attv1 = att[b * Ss + lane + 64];
        const int* ngp = ng + (size_t)(bp0 + wvid) * Cc * Ss;
        ngA0 = ngp[0*Ss + lane];      ngB0 = ngp[0*Ss + lane + 64];
        ngA1 = ngp[1*Ss + lane];      ngB1 = ngp[1*Ss + lane + 64];
        ngA2 = ngp[2*Ss + lane];      ngB2 = ngp[2*Ss + lane + 64];
        ngA3 = ngp[3*Ss + lane];      ngB3 = ngp[3*Ss + lane + 64];
        ngA4 = ngp[4*Ss + lane];      ngB4 = ngp[4*Ss + lane + 64];
    }
    if (wvid == 2) {       // sumW from staged LDS copy (no global traffic)
        float s = 0.f;
        #pragma unroll
        for (int i = 0; i < Hh / 64; ++i) s += wS[lane + i * 64];
        #pragma unroll
        for (int off = 32; off; off >>= 1) s += __shfl_xor(s, off, 64);
        if (lane == 0) swr_s = s;
    }
    SB                     // keep the above issued before the main loop

    CONSUMEG(A, 0)  LOADG4(A, 2)  SB
    CONSUMEG(B, 1)  LOADG4(B, 3)  SB
    CONSUMEG(A, 2)  LOADG4(A, 4)  SB
    CONSUMEG(B, 3)  LOADG4(B, 5)  SB
    CONSUMEG(A, 4)
    CONSUMEG(B, 5)

    partial[0][wvid][lane]      = acE00 + acO00;
    partial[0][wvid][lane + 64] = acE01 + acO01;
    partial[1][wvid][lane]      = acE10 + acO10;
    partial[1][wvid][lane + 64] = acE11 + acO11;
    __syncthreads();

    if (wvid < 2) {        // two-wave epilogue: wave p handles row p
        const int p = wvid;
        const size_t obase = ((size_t)(bp0 + p) * Cc + c) * Ss;
        const float tg0 = target[obase + lane];        // issue early
        const float tg1 = target[obase + lane + 64];
        float f0 = 0.f, f1 = 0.f;
        #pragma unroll
        for (int k = 0; k < 8; ++k) {                  // k=0 is wave0 -> same
            f0 += partial[p][k][lane];                 // add order as before
            f1 += partial[p][k][lane + 64];
        }
        const int any0 = (ngA0 | ngA1 | ngA2 | ngA3 | ngA4) & (attv0 > 0 ? -1 : 0);
        const int any1 = (ngB0 | ngB1 | ngB2 | ngB3 | ngB4) & (attv1 > 0 ? -1 : 0);
        const float mk0 = any0 ? 0.0f : NEGV;
        const float mk1 = any1 ? 0.0f : NEGV;
        const float l0 = swr_s - 2.0f * f0 + mk0;
        const float l1 = swr_s - 2.0f * f1 + mk1;
        out_logits[obase + lane]      = l0;
        out_logits[obase + lane + 64] = l1;
        float mx = fmaxf(l0, l1);
        #pragma unroll
        for (int off = 32; off; off >>= 1) mx = fmaxf(mx, __shfl_xor(mx, off, 64));
        const float e = __builtin_amdgcn_exp2f((l0 - mx) * 1.4426950408889634f)
                      + __builtin_amdgcn_exp2f((l1 - mx) * 1.4426950408889634f);
        float se = e, st = tg0 + tg1, sx = tg0 * l0 + tg1 * l1;
        #pragma unroll
        for (int off = 32; off; off >>= 1) {
            se += __shfl_xor(se, off, 64);
            st += __shfl_xor(st, off, 64);
            sx += __shfl_xor(sx, off, 64);
        }
        const float lse = mx + __builtin_amdgcn_logf(se) * 0.6931471805599453f;
        if (lane == 0) {   // bucketed fire-and-forget: no fence, no counter
            const int bkt = ((int)blockIdx.x & (NBUCKET - 1)) * 32;
            atomicAdd(&accumArr[bkt],     lse * st - sx);
            atomicAdd(&accumArr[bkt + 1], st);
        }
    }
}

// ---------------- Kernel 3: finalize (1 block, 64 thr) ----------------
__global__ __launch_bounds__(64)
void finalize_loss(const float* __restrict__ accumArr,
                   float* __restrict__ out_loss)
{
    const int lane = threadIdx.x;
    float n = 0.f, d = 0.f;
    if (lane < NBUCKET) { n = accumArr[lane * 32]; d = accumArr[lane * 32 + 1]; }
    #pragma unroll
    for (int off = 32; off; off >>= 1) {
        n += __shfl_xor(n, off, 64);
        d += __shfl_xor(d, off, 64);
    }
    if (lane == 0) out_loss[0] = n / d;
}

extern "C" void kernel_launch(void* const* d_in, const int* in_sizes, int n_in,
                              void* d_out, int out_size, void* d_ws, size_t ws_size,
                              hipStream_t stream) {
    const float* seq    = (const float*)d_in[0];
    const int*   att    = (const int*)  d_in[1];
    const int*   ng     = (const int*)  d_in[2];
    const float* target = (const float*)d_in[3];
    const float* Wprd   = (const float*)d_in[4];
    const float* bprd   = (const float*)d_in[5];
    const float* Warg   = (const float*)d_in[6];
    const float* barg   = (const float*)d_in[7];
    const float* Wout   = (const float*)d_in[8];

    float*  out      = (float*)d_out;
    float*  EpG      = (float*)d_ws;                     // 196608 floats
    ushort* haTb     = (ushort*)(EpG + 196608);          // 983040 ushorts
    float*  accumArr = EpG + 196608 + 491520;            // 1024 floats (32 buckets x 128B)

    gemm_mfma<<<dim3(144, 4), 256, 0, stream>>>(seq, Wprd, Warg, bprd, barg,
                                                EpG, haTb, accumArr);
    biaffine_loss<<<dim3(NBLK), 512, 0, stream>>>(EpG, haTb, Wout, ng, att, target,
                                                  out + 1, accumArr);
    finalize_loss<<<1, 64, 0, stream>>>(accumArr, out);
}